// Round 2
// baseline (443.851 us; speedup 1.0000x reference)
//
#include <hip/hip_runtime.h>

#define N_NODES_C 500000
#define NODE_DIM_C 128
#define HIDDEN_C 64
#define N_GRAPHS_C 16384

typedef __attribute__((ext_vector_type(2))) float f2;

// Prep: transpose W1 [64][128] -> W1T [128][64] into ws; zero the totals
// region of d_out (harness re-poisons d_out to 0xAA before every launch).
__global__ void prep_kernel(const float* __restrict__ W1,
                            float* __restrict__ W1T,
                            float* __restrict__ total) {
    int i = blockIdx.x * 256 + threadIdx.x;
    if (i < N_GRAPHS_C) total[i] = 0.0f;
    if (i < NODE_DIM_C * HIDDEN_C) {
        int k = i >> 6;   // / HIDDEN_C
        int h = i & 63;   // % HIDDEN_C
        W1T[i] = W1[h * NODE_DIM_C + k];
    }
}

// Fused: per-node MLP (128->64, SiLU, 64->1) + residual + sorted-segment sum.
// thread = node; 32 packed f32 accumulator pairs updated by v_pk_fma_f32
// (2 FMAs/instr); weights come in through the scalar pipe as SGPR pairs
// (uniform-indexed loads -> s_load), x row streamed as float4 with 2-stage
// prefetch.
__global__ __launch_bounds__(256, 4) void energy_kernel(
    const float* __restrict__ x,
    const float* __restrict__ ae_in,
    const int* __restrict__ batch,
    const float* __restrict__ W1T,
    const float* __restrict__ b1,
    const float* __restrict__ W2,
    const float* __restrict__ b2,
    float* __restrict__ out_ae,
    float* __restrict__ out_total)
{
    const int n = blockIdx.x * 256 + threadIdx.x;
    const bool active = (n < N_NODES_C);
    const int nc = active ? n : (N_NODES_C - 1);

    f2 acc[HIDDEN_C / 2];
    {
        const f2* b12 = reinterpret_cast<const f2*>(b1);
#pragma unroll
        for (int j = 0; j < HIDDEN_C / 2; ++j) acc[j] = b12[j];
    }

    const float4* xr = reinterpret_cast<const float4*>(x + (size_t)nc * NODE_DIM_C);

    // 2-stage prefetch of the node row, 16 floats (64 B) per stage.
    float4 c0 = xr[0], c1 = xr[1], c2 = xr[2], c3 = xr[3];

#pragma unroll 1
    for (int kc = 0; kc < NODE_DIM_C; kc += 16) {
        const int nk = ((kc + 16) & (NODE_DIM_C - 1)) >> 2;  // wraps on last iter (cheap L1 hit)
        float4 n0 = xr[nk + 0], n1 = xr[nk + 1], n2 = xr[nk + 2], n3 = xr[nk + 3];

        const float xk[16] = {c0.x, c0.y, c0.z, c0.w, c1.x, c1.y, c1.z, c1.w,
                              c2.x, c2.y, c2.z, c2.w, c3.x, c3.y, c3.z, c3.w};
#pragma unroll
        for (int kk = 0; kk < 16; ++kk) {
            // wave-uniform index -> scalar loads; each f2 weight pair is the
            // single SGPR-pair source of a v_pk_fma_f32.
            const f2* w2 = reinterpret_cast<const f2*>(W1T + (size_t)(kc + kk) * HIDDEN_C);
            const float xv = xk[kk];
            f2 xx;
            xx.x = xv; xx.y = xv;
#pragma unroll
            for (int j = 0; j < HIDDEN_C / 2; ++j) {
                f2 w = w2[j];
                // acc = w * xx + acc   (2 FP32 FMAs per instruction)
                asm("v_pk_fma_f32 %0, %1, %2, %0"
                    : "+v"(acc[j])
                    : "s"(w), "v"(xx));
            }
        }
        c0 = n0; c1 = n1; c2 = n2; c3 = n3;
    }

    // Epilogue: SiLU + dot with W2 + b2.
    float e = b2[0];
    {
        const f2* w22 = reinterpret_cast<const f2*>(W2);
#pragma unroll
        for (int j = 0; j < HIDDEN_C / 2; ++j) {
            f2 w = w22[j];
#pragma unroll
            for (int q = 0; q < 2; ++q) {
                float v = (q == 0) ? acc[j].x : acc[j].y;
                float wq = (q == 0) ? w.x : w.y;
                float ex = __expf(-v);                        // v_exp_f32 path
                float sig = __builtin_amdgcn_rcpf(1.0f + ex); // v_rcp_f32
                e = fmaf(wq * v, sig, e);                     // w * silu(v)
            }
        }
    }

    float ae = ae_in[nc] + e;
    if (active) out_ae[n] = ae;

    // Sorted-segment sum: wave-level segmented inclusive scan, then one
    // atomic per run boundary. Inactive lanes carry g=-1 / val=0 (no early
    // return so shuffles stay wave-converged).
    int g = active ? batch[n] : -1;
    float val = active ? ae : 0.0f;
    const int lane = threadIdx.x & 63;
#pragma unroll
    for (int off = 1; off < 64; off <<= 1) {
        float o = __shfl_up(val, off, 64);
        int og = __shfl_up(g, off, 64);
        if (lane >= off && og == g) val += o;
    }
    int gn = __shfl_down(g, 1, 64);
    bool lastlane = (lane == 63) || (gn != g);
    if (lastlane && g >= 0) atomicAdd(&out_total[g], val);
}

extern "C" void kernel_launch(void* const* d_in, const int* in_sizes, int n_in,
                              void* d_out, int out_size, void* d_ws, size_t ws_size,
                              hipStream_t stream) {
    const float* x     = (const float*)d_in[0];
    const float* ae    = (const float*)d_in[1];
    const int*   batch = (const int*)d_in[2];
    const float* W1    = (const float*)d_in[3];
    const float* b1    = (const float*)d_in[4];
    const float* W2    = (const float*)d_in[5];
    const float* b2    = (const float*)d_in[6];

    float* out_ae    = (float*)d_out;
    float* out_total = out_ae + N_NODES_C;
    float* W1T       = (float*)d_ws;   // 128*64*4 = 32 KB scratch

    prep_kernel<<<64, 256, 0, stream>>>(W1, W1T, out_total);

    const int blocks = (N_NODES_C + 255) / 256;
    energy_kernel<<<blocks, 256, 0, stream>>>(x, ae, batch, W1T, b1, W2, b2,
                                              out_ae, out_total);
}

// Round 5
// 425.990 us; speedup vs baseline: 1.0419x; 1.0419x over previous
//
#include <hip/hip_runtime.h>

#define N_NODES_C 500000
#define NODE_DIM_C 128
#define HIDDEN_C 64
#define N_GRAPHS_C 16384

typedef __attribute__((ext_vector_type(2))) float f2;

// Zero the totals region of d_out (harness re-poisons d_out to 0xAA before
// every launch).
__global__ void prep_kernel(float* __restrict__ total) {
    int i = blockIdx.x * 256 + threadIdx.x;
    if (i < N_GRAPHS_C) total[i] = 0.0f;
}

// Fused: per-node MLP (128->64, SiLU, 64->1) + residual + sorted-segment sum.
// thread = node; 32 packed f32 accumulator pairs updated by v_pk_fma_f32
// (2 FMAs/instr). Weights live in LDS (staged once per block); inner-loop
// reads are all-lanes-same-address ds_read_b128 -> hardware broadcast, no
// bank conflicts. x row streamed as float4 with 2-stage prefetch (each 128B
// line fully consumed by its owning thread).
__global__ __launch_bounds__(256, 3) void energy_kernel(
    const float* __restrict__ x,
    const float* __restrict__ ae_in,
    const int* __restrict__ batch,
    const float* __restrict__ W1,     // [64][128] original layout
    const float* __restrict__ b1,
    const float* __restrict__ W2,
    const float* __restrict__ b2,
    float* __restrict__ out_ae,
    float* __restrict__ out_total)
{
    __shared__ float wlds[NODE_DIM_C * HIDDEN_C];  // 32 KB: [k][h]

    // Cooperative transpose W1[h][k] -> wlds[k*64+h]. Coalesced global reads;
    // one-time cost amortized over the ~10k-cycle k-loop.
    for (int i = threadIdx.x; i < NODE_DIM_C * HIDDEN_C; i += 256) {
        int h = i >> 7;     // / 128
        int k = i & 127;    // % 128
        wlds[k * HIDDEN_C + h] = W1[i];
    }
    __syncthreads();

    const int n = blockIdx.x * 256 + threadIdx.x;
    const bool active = (n < N_NODES_C);
    const int nc = active ? n : (N_NODES_C - 1);

    f2 acc[HIDDEN_C / 2];
    {
        const f2* b12 = reinterpret_cast<const f2*>(b1);
#pragma unroll
        for (int j = 0; j < HIDDEN_C / 2; ++j) acc[j] = b12[j];
    }

    const float4* xr = reinterpret_cast<const float4*>(x + (size_t)nc * NODE_DIM_C);

    // 2-stage prefetch of the node row, 16 floats (64 B) per stage.
    float4 c0 = xr[0], c1 = xr[1], c2 = xr[2], c3 = xr[3];

#pragma unroll 1
    for (int kc = 0; kc < NODE_DIM_C; kc += 16) {
        const int nk = ((kc + 16) & (NODE_DIM_C - 1)) >> 2;  // wraps on last iter (L1 hit)
        float4 n0 = xr[nk + 0], n1 = xr[nk + 1], n2 = xr[nk + 2], n3 = xr[nk + 3];

        const float xk[16] = {c0.x, c0.y, c0.z, c0.w, c1.x, c1.y, c1.z, c1.w,
                              c2.x, c2.y, c2.z, c2.w, c3.x, c3.y, c3.z, c3.w};
#pragma unroll
        for (int kk = 0; kk < 16; ++kk) {
            // All lanes read the same LDS address -> broadcast, conflict-free.
            const float4* w4 = reinterpret_cast<const float4*>(&wlds[(kc + kk) * HIDDEN_C]);
            const float xv = xk[kk];
            f2 xx;
            xx.x = xv; xx.y = xv;
#pragma unroll
            for (int j = 0; j < HIDDEN_C / 4; ++j) {
                float4 w = w4[j];
                f2 wa; wa.x = w.x; wa.y = w.y;
                f2 wb; wb.x = w.z; wb.y = w.w;
                // acc = w * xx + acc   (2 FP32 FMAs per instruction)
                asm("v_pk_fma_f32 %0, %1, %2, %0"
                    : "+v"(acc[2 * j])
                    : "v"(wa), "v"(xx));
                asm("v_pk_fma_f32 %0, %1, %2, %0"
                    : "+v"(acc[2 * j + 1])
                    : "v"(wb), "v"(xx));
            }
        }
        c0 = n0; c1 = n1; c2 = n2; c3 = n3;
    }

    // Epilogue: SiLU + dot with W2 + b2.
    float e = b2[0];
    {
        const f2* w22 = reinterpret_cast<const f2*>(W2);
#pragma unroll
        for (int j = 0; j < HIDDEN_C / 2; ++j) {
            f2 w = w22[j];
#pragma unroll
            for (int q = 0; q < 2; ++q) {
                float v = (q == 0) ? acc[j].x : acc[j].y;
                float wq = (q == 0) ? w.x : w.y;
                float ex = __expf(-v);                        // v_exp_f32 path
                float sig = __builtin_amdgcn_rcpf(1.0f + ex); // v_rcp_f32
                e = fmaf(wq * v, sig, e);                     // w * silu(v)
            }
        }
    }

    float ae = ae_in[nc] + e;
    if (active) out_ae[n] = ae;

    // Sorted-segment sum: wave-level segmented inclusive scan, then one
    // atomic per run boundary. Inactive lanes carry g=-1 / val=0 (no early
    // return so shuffles stay wave-converged).
    int g = active ? batch[n] : -1;
    float val = active ? ae : 0.0f;
    const int lane = threadIdx.x & 63;
#pragma unroll
    for (int off = 1; off < 64; off <<= 1) {
        float o = __shfl_up(val, off, 64);
        int og = __shfl_up(g, off, 64);
        if (lane >= off && og == g) val += o;
    }
    int gn = __shfl_down(g, 1, 64);
    bool lastlane = (lane == 63) || (gn != g);
    if (lastlane && g >= 0) atomicAdd(&out_total[g], val);
}

extern "C" void kernel_launch(void* const* d_in, const int* in_sizes, int n_in,
                              void* d_out, int out_size, void* d_ws, size_t ws_size,
                              hipStream_t stream) {
    const float* x     = (const float*)d_in[0];
    const float* ae    = (const float*)d_in[1];
    const int*   batch = (const int*)d_in[2];
    const float* W1    = (const float*)d_in[3];
    const float* b1    = (const float*)d_in[4];
    const float* W2    = (const float*)d_in[5];
    const float* b2    = (const float*)d_in[6];

    float* out_ae    = (float*)d_out;
    float* out_total = out_ae + N_NODES_C;

    prep_kernel<<<64, 256, 0, stream>>>(out_total);

    const int blocks = (N_NODES_C + 255) / 256;
    energy_kernel<<<blocks, 256, 0, stream>>>(x, ae, batch, W1, b1, W2, b2,
                                              out_ae, out_total);
}